// Round 3
// baseline (35.428 us; speedup 1.0000x reference)
//
#include <hip/hip_runtime.h>

#define MARGIN 0.15f
#define EPS 1e-8f
#define D 256            // feature dim (fixed: samples are [512, 256] f32)
#define GT 32            // gram tile
#define LDP (D + 4)      // padded LDS row stride (floats), 16B-aligned rows
#define FP_SCALE 4294967296.0   // 2^32 fixed-point scale for deterministic i64 reduce
#define FP_INV   (1.0 / 4294967296.0)

// ---------------------------------------------------------------------------
// Kernel 1: fused row-norm + Gram tile.  G[a,b] = dot(X_a,X_b)/max(|a||b|,EPS)
// (exactly the reference's cosine-similarity formula).  32x32 output tile per
// 256-thread block, 2x2 per thread, both row-tiles staged in LDS; row norms
// computed in-block from the staged tiles.  Block (0,0) zeroes the i64
// accumulator + block counter for kernel 2 (stream-ordered handoff).
// ---------------------------------------------------------------------------
__global__ __launch_bounds__(256) void norm_gram(const float* __restrict__ X,
                                                 float* __restrict__ G,
                                                 unsigned long long* __restrict__ acc,
                                                 unsigned int* __restrict__ counter,
                                                 int N) {
    __shared__ float As[GT][LDP];
    __shared__ float Bs[GT][LDP];
    __shared__ float na[GT], nb[GT];
    int t = threadIdx.x;
    if (blockIdx.x == 0 && blockIdx.y == 0 && t == 0) {
        *acc = 0ull;
        *counter = 0u;
    }

    const float4* A4 = (const float4*)(X + (size_t)blockIdx.y * GT * D);
    const float4* B4 = (const float4*)(X + (size_t)blockIdx.x * GT * D);
#pragma unroll
    for (int i = 0; i < 8; ++i) {
        int f = t + i * 256;          // 0..2047 float4s per 32x256 tile
        int r = f >> 6, c = f & 63;
        *(float4*)&As[r][c * 4] = A4[f];
        *(float4*)&Bs[r][c * 4] = B4[f];
    }
    __syncthreads();

    // Row norms from LDS: 8 adjacent lanes per row.
    {
        int row = t >> 3, sub = t & 7;
        float ssA = 0.f, ssB = 0.f;
#pragma unroll
        for (int j = 0; j < 8; ++j) {
            float4 a = *(const float4*)&As[row][(sub * 8 + j) * 4];
            ssA += a.x * a.x + a.y * a.y + a.z * a.z + a.w * a.w;
            float4 b = *(const float4*)&Bs[row][(sub * 8 + j) * 4];
            ssB += b.x * b.x + b.y * b.y + b.z * b.z + b.w * b.w;
        }
#pragma unroll
        for (int off = 1; off < 8; off <<= 1) {
            ssA += __shfl_xor(ssA, off);
            ssB += __shfl_xor(ssB, off);
        }
        if (sub == 0) { na[row] = sqrtf(ssA); nb[row] = sqrtf(ssB); }
    }
    __syncthreads();

    int tx = t & 15, ty = t >> 4;
    int r0 = ty * 2, c0 = tx * 2;
    float acc00 = 0.f, acc01 = 0.f, acc10 = 0.f, acc11 = 0.f;
#pragma unroll 4
    for (int k = 0; k < D; k += 4) {
        float4 a0 = *(const float4*)&As[r0][k];
        float4 a1 = *(const float4*)&As[r0 + 1][k];
        float4 b0 = *(const float4*)&Bs[c0][k];
        float4 b1 = *(const float4*)&Bs[c0 + 1][k];
        acc00 += a0.x * b0.x + a0.y * b0.y + a0.z * b0.z + a0.w * b0.w;
        acc01 += a0.x * b1.x + a0.y * b1.y + a0.z * b1.z + a0.w * b1.w;
        acc10 += a1.x * b0.x + a1.y * b0.y + a1.z * b0.z + a1.w * b0.w;
        acc11 += a1.x * b1.x + a1.y * b1.y + a1.z * b1.z + a1.w * b1.w;
    }
    float nA0 = na[r0], nA1 = na[r0 + 1], nB0 = nb[c0], nB1 = nb[c0 + 1];
    size_t orow = (size_t)(blockIdx.y * GT + r0) * N + blockIdx.x * GT + c0;
    float2 o0 = {acc00 / fmaxf(nA0 * nB0, EPS), acc01 / fmaxf(nA0 * nB1, EPS)};
    float2 o1 = {acc10 / fmaxf(nA1 * nB0, EPS), acc11 / fmaxf(nA1 * nB1, EPS)};
    *(float2*)&G[orow]     = o0;
    *(float2*)&G[orow + N] = o1;
}

// ---------------------------------------------------------------------------
// Kernel 2: per-triplet hinge from G + fence-free deterministic grid reduce.
// d_pos - d_neg + m = G[a,n] - G[a,p] + m.  Block partial (fixed-order f32
// shuffle tree) -> fixed-point u64 -> one atomicAdd at the LLC.  The acc-add's
// returned value is consumed before the counter bump, so the add is complete
// (LLC-visible) before counter increments; the last block reads the total
// with atomicAdd(acc, 0).  No __threadfence anywhere.
// ---------------------------------------------------------------------------
__global__ __launch_bounds__(256) void triplet_acc(const float* __restrict__ G,
                                                   const int* __restrict__ ai,
                                                   const int* __restrict__ pi,
                                                   const int* __restrict__ ni,
                                                   unsigned long long* __restrict__ acc,
                                                   unsigned int* __restrict__ counter,
                                                   int T, int N, int NB, float invT,
                                                   float* __restrict__ out) {
    float sum = 0.f;
    for (int t = blockIdx.x * blockDim.x + threadIdx.x; t < T;
         t += gridDim.x * blockDim.x) {
        int a = ai[t], p = pi[t], n = ni[t];
        float gan = G[(size_t)a * N + n];
        float gap = G[(size_t)a * N + p];
        float v = gan - gap + MARGIN;
        sum += v > 0.f ? v : 0.f;
    }
#pragma unroll
    for (int off = 32; off; off >>= 1) sum += __shfl_xor(sum, off);
    __shared__ float red[4];
    int wid = threadIdx.x >> 6;
    if ((threadIdx.x & 63) == 0) red[wid] = sum;
    __syncthreads();
    if (threadIdx.x == 0) {
        float bsum = red[0] + red[1] + red[2] + red[3];   // >= 0 (hinge)
        unsigned long long iv = (unsigned long long)((double)bsum * FP_SCALE);
        unsigned long long old = atomicAdd(acc, iv);
        // Consume the returned value: forces s_waitcnt on the atomic before
        // anything below issues; "memory" stops reordering of the counter add.
        asm volatile("" :: "v"(old) : "memory");
        unsigned int done = atomicAdd(counter, 1u);
        if (done == (unsigned int)(NB - 1)) {
            unsigned long long tot = atomicAdd(acc, 0ull);  // atomic read @ LLC
            out[0] = (float)((double)tot * FP_INV * (double)invT);
        }
    }
}

// ---------------------------------------------------------------------------
// Fallback kernels (small ws): norms + direct per-triplet dots + reduce.
// ---------------------------------------------------------------------------
__global__ __launch_bounds__(256) void norm_rows(const float* __restrict__ X,
                                                 float* __restrict__ rnorm, int N) {
    int row = blockIdx.x * 4 + (threadIdx.x >> 6);
    if (row >= N) return;
    int lane = threadIdx.x & 63;
    float4 v = ((const float4*)(X + (size_t)row * D))[lane];
    float ss = v.x * v.x + v.y * v.y + v.z * v.z + v.w * v.w;
#pragma unroll
    for (int off = 32; off; off >>= 1) ss += __shfl_xor(ss, off);
    if (lane == 0) rnorm[row] = sqrtf(ss);
}

__global__ __launch_bounds__(256) void triplet_direct(const float* __restrict__ X,
                                                      const float* __restrict__ rnorm,
                                                      const int* __restrict__ ai,
                                                      const int* __restrict__ pi,
                                                      const int* __restrict__ ni,
                                                      float* __restrict__ partial,
                                                      int T, int N) {
    float sum = 0.f;
    for (int t = blockIdx.x * blockDim.x + threadIdx.x; t < T;
         t += gridDim.x * blockDim.x) {
        int a = ai[t], p = pi[t], n = ni[t];
        const float4* xa = (const float4*)(X + (size_t)a * D);
        const float4* xp = (const float4*)(X + (size_t)p * D);
        const float4* xn = (const float4*)(X + (size_t)n * D);
        float dp = 0.f, dn = 0.f;
#pragma unroll 4
        for (int k = 0; k < D / 4; ++k) {
            float4 av = xa[k], pv = xp[k], nv = xn[k];
            dp += av.x * pv.x + av.y * pv.y + av.z * pv.z + av.w * pv.w;
            dn += av.x * nv.x + av.y * nv.y + av.z * nv.z + av.w * nv.w;
        }
        float na = rnorm[a];
        float v = dn / fmaxf(na * rnorm[n], EPS) - dp / fmaxf(na * rnorm[p], EPS) + MARGIN;
        sum += v > 0.f ? v : 0.f;
    }
#pragma unroll
    for (int off = 32; off; off >>= 1) sum += __shfl_xor(sum, off);
    __shared__ float red[4];
    int wid = threadIdx.x >> 6;
    if ((threadIdx.x & 63) == 0) red[wid] = sum;
    __syncthreads();
    if (threadIdx.x == 0) partial[blockIdx.x] = red[0] + red[1] + red[2] + red[3];
}

__global__ __launch_bounds__(256) void reduce_partials(const float* __restrict__ partial,
                                                       int nb, float invT,
                                                       float* __restrict__ out) {
    float s = 0.f;
    for (int i = threadIdx.x; i < nb; i += 256) s += partial[i];
#pragma unroll
    for (int off = 32; off; off >>= 1) s += __shfl_xor(s, off);
    __shared__ float red[4];
    int wid = threadIdx.x >> 6;
    if ((threadIdx.x & 63) == 0) red[wid] = s;
    __syncthreads();
    if (threadIdx.x == 0) out[0] = (red[0] + red[1] + red[2] + red[3]) * invT;
}

extern "C" void kernel_launch(void* const* d_in, const int* in_sizes, int n_in,
                              void* d_out, int out_size, void* d_ws, size_t ws_size,
                              hipStream_t stream) {
    const float* X  = (const float*)d_in[0];   // samples [N, D] f32
    const int*   ai = (const int*)d_in[2];     // anchor_idx [T]
    const int*   pi = (const int*)d_in[3];     // pos_idx [T]
    const int*   ni = (const int*)d_in[4];     // neg_idx [T]
    float* out = (float*)d_out;

    int N = in_sizes[1];                       // 512
    int T = in_sizes[2];

    int NB = (T + 255) / 256;
    if (NB > 2048) NB = 2048;
    if (NB < 1) NB = 1;

    size_t gB = (size_t)N * N * sizeof(float);

    if (ws_size >= gB + 16 && (N % GT) == 0) {
        // Path A: fused norm+gram -> fused triplet + fence-free i64 reduce
        float*              G       = (float*)d_ws;
        unsigned long long* acc     = (unsigned long long*)((char*)d_ws + gB);
        unsigned int*       counter = (unsigned int*)((char*)d_ws + gB + 8);
        dim3 gg(N / GT, N / GT);
        norm_gram<<<gg, 256, 0, stream>>>(X, G, acc, counter, N);
        triplet_acc<<<NB, 256, 0, stream>>>(G, ai, pi, ni, acc, counter,
                                            T, N, NB, 1.0f / (float)T, out);
    } else {
        // Path B: norms + direct per-triplet dots + reduce (3 dispatches)
        float* rnorm   = (float*)d_ws;
        float* partial = rnorm + N;
        norm_rows<<<(N + 3) / 4, 256, 0, stream>>>(X, rnorm, N);
        triplet_direct<<<NB, 256, 0, stream>>>(X, rnorm, ai, pi, ni, partial, T, N);
        reduce_partials<<<1, 256, 0, stream>>>(partial, NB, 1.0f / (float)T, out);
    }
}

// Round 4
// 16.081 us; speedup vs baseline: 2.2031x; 2.2031x over previous
//
#include <hip/hip_runtime.h>

#define MARGIN 0.15f
#define EPS 1e-8f
#define D 256            // feature dim (fixed: samples are [512, 256] f32)
#define GT 32            // gram tile
#define LDP (D + 4)      // padded LDS row stride (floats), 16B-aligned rows

// ---------------------------------------------------------------------------
// Kernel 1: fused row-norm + Gram tile (proven in rounds 2/3, absmax 0.0).
// G[a,b] = dot(X_a,X_b)/max(|a||b|,EPS) — exactly the reference cosine form.
// 32x32 output tile per 256-thread block, 2x2 per thread, both row-tiles
// staged in LDS; row norms computed in-block from the staged tiles.
// No counters, no atomics.
// ---------------------------------------------------------------------------
__global__ __launch_bounds__(256) void norm_gram(const float* __restrict__ X,
                                                 float* __restrict__ G, int N) {
    __shared__ float As[GT][LDP];
    __shared__ float Bs[GT][LDP];
    __shared__ float na[GT], nb[GT];
    int t = threadIdx.x;

    const float4* A4 = (const float4*)(X + (size_t)blockIdx.y * GT * D);
    const float4* B4 = (const float4*)(X + (size_t)blockIdx.x * GT * D);
#pragma unroll
    for (int i = 0; i < 8; ++i) {
        int f = t + i * 256;          // 0..2047 float4s per 32x256 tile
        int r = f >> 6, c = f & 63;
        *(float4*)&As[r][c * 4] = A4[f];
        *(float4*)&Bs[r][c * 4] = B4[f];
    }
    __syncthreads();

    // Row norms from LDS: 8 adjacent lanes per row.
    {
        int row = t >> 3, sub = t & 7;
        float ssA = 0.f, ssB = 0.f;
#pragma unroll
        for (int j = 0; j < 8; ++j) {
            float4 a = *(const float4*)&As[row][(sub * 8 + j) * 4];
            ssA += a.x * a.x + a.y * a.y + a.z * a.z + a.w * a.w;
            float4 b = *(const float4*)&Bs[row][(sub * 8 + j) * 4];
            ssB += b.x * b.x + b.y * b.y + b.z * b.z + b.w * b.w;
        }
#pragma unroll
        for (int off = 1; off < 8; off <<= 1) {
            ssA += __shfl_xor(ssA, off);
            ssB += __shfl_xor(ssB, off);
        }
        if (sub == 0) { na[row] = sqrtf(ssA); nb[row] = sqrtf(ssB); }
    }
    __syncthreads();

    int tx = t & 15, ty = t >> 4;
    int r0 = ty * 2, c0 = tx * 2;
    float acc00 = 0.f, acc01 = 0.f, acc10 = 0.f, acc11 = 0.f;
#pragma unroll 4
    for (int k = 0; k < D; k += 4) {
        float4 a0 = *(const float4*)&As[r0][k];
        float4 a1 = *(const float4*)&As[r0 + 1][k];
        float4 b0 = *(const float4*)&Bs[c0][k];
        float4 b1 = *(const float4*)&Bs[c0 + 1][k];
        acc00 += a0.x * b0.x + a0.y * b0.y + a0.z * b0.z + a0.w * b0.w;
        acc01 += a0.x * b1.x + a0.y * b1.y + a0.z * b1.z + a0.w * b1.w;
        acc10 += a1.x * b0.x + a1.y * b0.y + a1.z * b0.z + a1.w * b0.w;
        acc11 += a1.x * b1.x + a1.y * b1.y + a1.z * b1.z + a1.w * b1.w;
    }
    float nA0 = na[r0], nA1 = na[r0 + 1], nB0 = nb[c0], nB1 = nb[c0 + 1];
    size_t orow = (size_t)(blockIdx.y * GT + r0) * N + blockIdx.x * GT + c0;
    float2 o0 = {acc00 / fmaxf(nA0 * nB0, EPS), acc01 / fmaxf(nA0 * nB1, EPS)};
    float2 o1 = {acc10 / fmaxf(nA1 * nB0, EPS), acc11 / fmaxf(nA1 * nB1, EPS)};
    *(float2*)&G[orow]     = o0;
    *(float2*)&G[orow + N] = o1;
}

// ---------------------------------------------------------------------------
// Kernel 2: per-triplet hinge from G, 2 triplets/thread via int2 index loads,
// deterministic fixed-order block reduce, plain partial store. No atomics.
// d_pos - d_neg + m = G[a,n] - G[a,p] + m.
// ---------------------------------------------------------------------------
__global__ __launch_bounds__(256) void triplet_g(const float* __restrict__ G,
                                                 const int* __restrict__ ai,
                                                 const int* __restrict__ pi,
                                                 const int* __restrict__ ni,
                                                 float* __restrict__ partial,
                                                 int T, int N) {
    const int2* ai2 = (const int2*)ai;
    const int2* pi2 = (const int2*)pi;
    const int2* ni2 = (const int2*)ni;
    int half = T >> 1;
    float sum = 0.f;
    int tid = blockIdx.x * blockDim.x + threadIdx.x;
    int stride = gridDim.x * blockDim.x;
    for (int t = tid; t < half; t += stride) {
        int2 a = ai2[t], p = pi2[t], n = ni2[t];
        float v0 = G[(size_t)a.x * N + n.x] - G[(size_t)a.x * N + p.x] + MARGIN;
        float v1 = G[(size_t)a.y * N + n.y] - G[(size_t)a.y * N + p.y] + MARGIN;
        sum += (v0 > 0.f ? v0 : 0.f) + (v1 > 0.f ? v1 : 0.f);
    }
    if (tid == 0 && (T & 1)) {
        int t = T - 1;
        float v = G[(size_t)ai[t] * N + ni[t]] - G[(size_t)ai[t] * N + pi[t]] + MARGIN;
        sum += v > 0.f ? v : 0.f;
    }
#pragma unroll
    for (int off = 32; off; off >>= 1) sum += __shfl_xor(sum, off);
    __shared__ float red[4];
    int wid = threadIdx.x >> 6;
    if ((threadIdx.x & 63) == 0) red[wid] = sum;
    __syncthreads();
    if (threadIdx.x == 0) partial[blockIdx.x] = red[0] + red[1] + red[2] + red[3];
}

// ---------------------------------------------------------------------------
// Kernel 3: fixed-order final reduce over block partials, scale by 1/T.
// ---------------------------------------------------------------------------
__global__ __launch_bounds__(256) void reduce_partials(const float* __restrict__ partial,
                                                       int nb, float invT,
                                                       float* __restrict__ out) {
    float s = 0.f;
    for (int i = threadIdx.x; i < nb; i += 256) s += partial[i];
#pragma unroll
    for (int off = 32; off; off >>= 1) s += __shfl_xor(s, off);
    __shared__ float red[4];
    int wid = threadIdx.x >> 6;
    if ((threadIdx.x & 63) == 0) red[wid] = s;
    __syncthreads();
    if (threadIdx.x == 0) out[0] = (red[0] + red[1] + red[2] + red[3]) * invT;
}

// ---------------------------------------------------------------------------
// Fallback kernels (small ws): norms + direct per-triplet dots + reduce.
// ---------------------------------------------------------------------------
__global__ __launch_bounds__(256) void norm_rows(const float* __restrict__ X,
                                                 float* __restrict__ rnorm, int N) {
    int row = blockIdx.x * 4 + (threadIdx.x >> 6);
    if (row >= N) return;
    int lane = threadIdx.x & 63;
    float4 v = ((const float4*)(X + (size_t)row * D))[lane];
    float ss = v.x * v.x + v.y * v.y + v.z * v.z + v.w * v.w;
#pragma unroll
    for (int off = 32; off; off >>= 1) ss += __shfl_xor(ss, off);
    if (lane == 0) rnorm[row] = sqrtf(ss);
}

__global__ __launch_bounds__(256) void triplet_direct(const float* __restrict__ X,
                                                      const float* __restrict__ rnorm,
                                                      const int* __restrict__ ai,
                                                      const int* __restrict__ pi,
                                                      const int* __restrict__ ni,
                                                      float* __restrict__ partial,
                                                      int T, int N) {
    float sum = 0.f;
    for (int t = blockIdx.x * blockDim.x + threadIdx.x; t < T;
         t += gridDim.x * blockDim.x) {
        int a = ai[t], p = pi[t], n = ni[t];
        const float4* xa = (const float4*)(X + (size_t)a * D);
        const float4* xp = (const float4*)(X + (size_t)p * D);
        const float4* xn = (const float4*)(X + (size_t)n * D);
        float dp = 0.f, dn = 0.f;
#pragma unroll 4
        for (int k = 0; k < D / 4; ++k) {
            float4 av = xa[k], pv = xp[k], nv = xn[k];
            dp += av.x * pv.x + av.y * pv.y + av.z * pv.z + av.w * pv.w;
            dn += av.x * nv.x + av.y * nv.y + av.z * nv.z + av.w * nv.w;
        }
        float na = rnorm[a];
        float v = dn / fmaxf(na * rnorm[n], EPS) - dp / fmaxf(na * rnorm[p], EPS) + MARGIN;
        sum += v > 0.f ? v : 0.f;
    }
#pragma unroll
    for (int off = 32; off; off >>= 1) sum += __shfl_xor(sum, off);
    __shared__ float red[4];
    int wid = threadIdx.x >> 6;
    if ((threadIdx.x & 63) == 0) red[wid] = sum;
    __syncthreads();
    if (threadIdx.x == 0) partial[blockIdx.x] = red[0] + red[1] + red[2] + red[3];
}

extern "C" void kernel_launch(void* const* d_in, const int* in_sizes, int n_in,
                              void* d_out, int out_size, void* d_ws, size_t ws_size,
                              hipStream_t stream) {
    const float* X  = (const float*)d_in[0];   // samples [N, D] f32
    const int*   ai = (const int*)d_in[2];     // anchor_idx [T]
    const int*   pi = (const int*)d_in[3];     // pos_idx [T]
    const int*   ni = (const int*)d_in[4];     // neg_idx [T]
    float* out = (float*)d_out;

    int N = in_sizes[1];                       // 512
    int T = in_sizes[2];

    size_t gB    = (size_t)N * N * sizeof(float);
    size_t partB = 2048 * sizeof(float);

    if (ws_size >= gB + partB && (N % GT) == 0) {
        // Path A: fused norm+gram -> triplet hinge (2/thread) -> 1-block reduce
        float* G       = (float*)d_ws;
        float* partial = (float*)((char*)d_ws + gB);
        int NB = ((T >> 1) + 255) / 256;
        if (NB > 2048) NB = 2048;
        if (NB < 1) NB = 1;
        dim3 gg(N / GT, N / GT);
        norm_gram<<<gg, 256, 0, stream>>>(X, G, N);
        triplet_g<<<NB, 256, 0, stream>>>(G, ai, pi, ni, partial, T, N);
        reduce_partials<<<1, 256, 0, stream>>>(partial, NB, 1.0f / (float)T, out);
    } else {
        // Path B: norms + direct per-triplet dots + reduce (3 dispatches)
        float* rnorm   = (float*)d_ws;
        float* partial = rnorm + N;
        int NB = (T + 255) / 256;
        if (NB > 2048) NB = 2048;
        if (NB < 1) NB = 1;
        norm_rows<<<(N + 3) / 4, 256, 0, stream>>>(X, rnorm, N);
        triplet_direct<<<NB, 256, 0, stream>>>(X, rnorm, ai, pi, ni, partial, T, N);
        reduce_partials<<<1, 256, 0, stream>>>(partial, NB, 1.0f / (float)T, out);
    }
}